// Round 3
// baseline (998.252 us; speedup 1.0000x reference)
//
#include <hip/hip_runtime.h>
#include <cstdint>

// Problem constants (fixed dataset: setup_inputs in reference)
constexpr int B = 8, N = 100000, G = 64, T = 256, TOPK = 27;
constexpr int BN = B * N;
constexpr int CAP = 2048;           // candidate LDS capacity per gt
#define NEG_INF_VAL (-100000000.0f) // -INF in reference, exactly representable

// ---------------------------------------------------------------------------
// Kernel P: fused prep — zero the best[] buffer and precompute anchor centers
// (same formula as assign/iou so distances are bit-identical).
// ---------------------------------------------------------------------------
__global__ __launch_bounds__(256) void atss_prep_kernel(
    const float* __restrict__ anchors, float2* __restrict__ ctr,
    unsigned long long* __restrict__ best)
{
#pragma clang fp contract(off)
  int i = blockIdx.x * 256 + threadIdx.x;
  if (i < BN) {
    best[i] = 0ULL;
    float4 ab = ((const float4*)anchors)[i];
    ctr[i] = make_float2((ab.z + ab.x) * 0.5f, (ab.w + ab.y) * 0.5f);
  }
}

// ---------------------------------------------------------------------------
// Kernel A: one block per (b,g). Exact top-27 nearest anchors by center
// distance (tie-break: lower index, matching lax.top_k), candidate IoUs,
// mean + unbiased std threshold (ddof=1), center-inside test, packed
// atomicMax scatter into per-anchor best buffer.
// packed = (f32bits(iou) << 32) | (0xFFFFFFFF - g)
//   -> max = largest iou; tie -> smallest g (matches jnp.argmax first-max).
// packed == 0 means "unmatched" (positives always have iou > 0).
// NUMERICS UNCHANGED from round 2 (absmax 0.0) — do not touch.
// ---------------------------------------------------------------------------
__global__ __launch_bounds__(256) void atss_assign_kernel(
    const float* __restrict__ anchors,     // [B,N,4]
    const float2* __restrict__ ctr,        // [B,N]
    const float* __restrict__ gts,         // [B,G,4]
    unsigned long long* __restrict__ best) // [B*N]
{
#pragma clang fp contract(off)
  __shared__ float s_d[CAP];
  __shared__ int   s_i[CAP];
  __shared__ int   s_cnt;
  __shared__ int   s_sel[TOPK];
  __shared__ float s_iou[TOPK];
  __shared__ int   s_in[TOPK];
  __shared__ float s_thresh;

  const int bg  = blockIdx.x;
  const int b   = bg / G;
  const int g   = bg % G;
  const int tid = threadIdx.x;

  const float4 gbox = ((const float4*)gts)[bg];
  const float g_cx = (gbox.z + gbox.x) * 0.5f;
  const float g_cy = (gbox.w + gbox.y) * 0.5f;

  const float4*  abase = (const float4*)(anchors + (size_t)b * N * 4);
  const float2*  cbase = ctr + (size_t)b * N;

  // --- Candidate collection: all anchors with dist < thr (exact count). ---
  float thr = 24.0f;
  int M = 0;
  for (int attempt = 0; attempt < 8; ++attempt) {
    if (tid == 0) s_cnt = 0;
    __syncthreads();
    for (int n = tid; n < N; n += 256) {
      float2 c = cbase[n];
      float dx = c.x - g_cx, dy = c.y - g_cy;
      float d = __fsqrt_rn(__fmul_rn(dx, dx) + __fmul_rn(dy, dy));
      if (d < thr) {
        int p = atomicAdd(&s_cnt, 1);
        if (p < CAP) { s_d[p] = d; s_i[p] = n; }
      }
    }
    __syncthreads();
    int cnt = s_cnt;
    __syncthreads();
    if (cnt >= TOPK && cnt <= CAP) { M = cnt; break; }
    thr = (cnt < TOPK) ? thr * 4.0f : thr * 0.5f;
  }

  // --- Exact top-27 by rank counting over (d, idx) lexicographic keys. ---
  for (int s = tid; s < M; s += 256) {
    unsigned long long pk_s =
        ((unsigned long long)__float_as_uint(s_d[s]) << 20) |
        (unsigned long long)(unsigned)s_i[s];
    int rank = 0;
    for (int j = 0; j < M; ++j) {
      unsigned long long pk_j =
          ((unsigned long long)__float_as_uint(s_d[j]) << 20) |
          (unsigned long long)(unsigned)s_i[j];
      rank += (pk_j < pk_s) ? 1 : 0;
    }
    if (rank < TOPK) s_sel[rank] = s_i[s];
  }
  __syncthreads();

  // --- Candidate IoU + center-inside test. ---
  if (tid < TOPK) {
    int a = s_sel[tid];
    float4 ab = abase[a];
    float area_a = __fmul_rn(ab.z - ab.x, ab.w - ab.y);
    float area_b = __fmul_rn(gbox.z - gbox.x, gbox.w - gbox.y);
    float ltx = fmaxf(ab.x, gbox.x), lty = fmaxf(ab.y, gbox.y);
    float rbx = fminf(ab.z, gbox.z), rby = fminf(ab.w, gbox.w);
    float w = fmaxf(rbx - ltx, 0.0f), h = fmaxf(rby - lty, 0.0f);
    float inter = __fmul_rn(w, h);
    float uni = (area_a + area_b) - inter;
    s_iou[tid] = inter / uni;
    float acx = (ab.z + ab.x) * 0.5f, acy = (ab.w + ab.y) * 0.5f;
    float l = acx - gbox.x, t = acy - gbox.y;
    float r = gbox.z - acx, bt = gbox.w - acy;
    float mn = fminf(fminf(l, t), fminf(r, bt));
    s_in[tid] = (mn > 0.01f) ? 1 : 0;
  }
  __syncthreads();

  // --- mean + unbiased std threshold (ddof=1). ---
  if (tid == 0) {
    float sum = 0.0f;
    for (int k = 0; k < TOPK; ++k) sum += s_iou[k];
    float mean = sum / (float)TOPK;
    float vs = 0.0f;
    for (int k = 0; k < TOPK; ++k) {
      float d = s_iou[k] - mean;
      vs += __fmul_rn(d, d);
    }
    float sd = __fsqrt_rn(vs / (float)(TOPK - 1));
    s_thresh = mean + sd;
  }
  __syncthreads();

  // --- Scatter positives. ---
  if (tid < TOPK) {
    float iou = s_iou[tid];
    if (s_in[tid] && iou >= s_thresh) {
      unsigned long long pk =
          ((unsigned long long)__float_as_uint(iou) << 32) |
          (unsigned long long)(0xFFFFFFFFu - (unsigned)g);
      atomicMax(&best[(size_t)b * N + s_sel[tid]], pk);
    }
  }
}

// ---------------------------------------------------------------------------
// Kernel W: SPARSE writer. Token region is pre-zeroed by hipMemsetAsync
// (runs at the proven 6.2 TB/s fill rate); this kernel writes only:
//  - val / idx (coalesced dword), matched_gts (coalesced float4)
//  - 1.0f at token column T-1 for unmatched anchors (~98.3%)
//  - full 1 KB token rows for matched anchors (~1.7%), wave-cooperative
// ---------------------------------------------------------------------------
__global__ __launch_bounds__(256) void atss_sparse_write_kernel(
    const unsigned long long* __restrict__ best, // [B*N]
    const float* __restrict__ gts,               // [B,G,4]
    const float* __restrict__ tokens,            // [B,G,T]
    float* __restrict__ out)
{
  float* __restrict__ out_val = out;
  float* __restrict__ out_idx = out + (size_t)BN;
  float* __restrict__ out_mg  = out + (size_t)2 * BN;
  float* __restrict__ out_tok = out + (size_t)6 * BN;

  __shared__ int s_m_anchor[256]; // global anchor idx of matched anchors
  __shared__ int s_m_row[256];    // their gt row (b*G+g)
  __shared__ int s_m_cnt;

  const int tid = threadIdx.x;
  const int i0  = blockIdx.x * 256;
  const int i   = i0 + tid;

  if (tid == 0) s_m_cnt = 0;
  __syncthreads();

  unsigned long long p = best[i];
  const int b_ = i / N;
  int g = 0;
  float val = NEG_INF_VAL;
  if (p != 0ULL) {
    g   = (int)(0xFFFFFFFFu - (unsigned)(p & 0xFFFFFFFFULL));
    val = __uint_as_float((unsigned)(p >> 32));
  }
  const int row = b_ * G + g; // unmatched -> g=0 (matches argmax of all -INF)

  out_val[i] = val;
  out_idx[i] = (float)g;
  ((float4*)out_mg)[i] = ((const float4*)gts)[row];

  if (p != 0ULL) {
    int s = atomicAdd(&s_m_cnt, 1);
    s_m_anchor[s] = i;
    s_m_row[s]    = row;
  } else {
    out_tok[(size_t)i * T + (T - 1)] = 1.0f; // one-hot on pre-zeroed row
  }
  __syncthreads();

  // Wave-cooperative full-row copies for matched anchors (1 KB each).
  const int lane = tid & 63;
  const int wv   = tid >> 6;
  const int cnt  = s_m_cnt;
  const float4* tok4 = (const float4*)tokens;
  for (int s = wv; s < cnt; s += 4) {
    const int a = s_m_anchor[s];
    const int r = s_m_row[s];
    ((float4*)(out_tok + (size_t)a * T))[lane] = tok4[(size_t)r * 64 + lane];
  }
}

extern "C" void kernel_launch(void* const* d_in, const int* in_sizes, int n_in,
                              void* d_out, int out_size, void* d_ws, size_t ws_size,
                              hipStream_t stream) {
  const float* anchors = (const float*)d_in[0]; // [B,N,4]
  const float* gts     = (const float*)d_in[1]; // [B,G,4]
  const float* tokens  = (const float*)d_in[2]; // [B,G,T]
  float* out = (float*)d_out;

  unsigned long long* best = (unsigned long long*)d_ws;        // B*N u64 = 6.4 MB
  float2* ctr = (float2*)((char*)d_ws + sizeof(unsigned long long) * (size_t)BN);

  // Zero the token-label region (819.2 MB) at fill-kernel rate; the sparse
  // writer then touches only ~85 MB.
  hipMemsetAsync(out + (size_t)6 * BN, 0, sizeof(float) * (size_t)BN * T, stream);

  atss_prep_kernel<<<(BN + 255) / 256, 256, 0, stream>>>(anchors, ctr, best);
  atss_assign_kernel<<<B * G, 256, 0, stream>>>(anchors, ctr, gts, best);
  atss_sparse_write_kernel<<<BN / 256, 256, 0, stream>>>(best, gts, tokens, out);
}

// Round 4
// 979.672 us; speedup vs baseline: 1.0190x; 1.0190x over previous
//
#include <hip/hip_runtime.h>
#include <cstdint>

// Problem constants (fixed dataset: setup_inputs in reference)
constexpr int B = 8, N = 100000, G = 64, T = 256, TOPK = 27;
constexpr int BN = B * N;
constexpr int CAP = 2048;           // candidate LDS capacity per gt
#define NEG_INF_VAL (-100000000.0f) // -INF in reference, exactly representable

// ---------------------------------------------------------------------------
// Kernel P: fused prep — zero the best[] buffer and precompute anchor centers
// (same formula as assign/iou so distances are bit-identical).
// ---------------------------------------------------------------------------
__global__ __launch_bounds__(256) void atss_prep_kernel(
    const float* __restrict__ anchors, float2* __restrict__ ctr,
    unsigned long long* __restrict__ best)
{
#pragma clang fp contract(off)
  int i = blockIdx.x * 256 + threadIdx.x;
  if (i < BN) {
    best[i] = 0ULL;
    float4 ab = ((const float4*)anchors)[i];
    ctr[i] = make_float2((ab.z + ab.x) * 0.5f, (ab.w + ab.y) * 0.5f);
  }
}

// ---------------------------------------------------------------------------
// Kernel A: one block per (b,g). Exact top-27 nearest anchors by center
// distance (tie-break: lower index, matching lax.top_k), candidate IoUs,
// mean + unbiased std threshold (ddof=1), center-inside test, packed
// atomicMax scatter into per-anchor best buffer.
// packed = (f32bits(iou) << 32) | (0xFFFFFFFF - g)
//   -> max = largest iou; tie -> smallest g (matches jnp.argmax first-max).
// packed == 0 means "unmatched" (positives always have iou > 0).
// NUMERICS UNCHANGED since round 2 (absmax 0.0) — do not touch.
// ---------------------------------------------------------------------------
__global__ __launch_bounds__(256) void atss_assign_kernel(
    const float* __restrict__ anchors,     // [B,N,4]
    const float2* __restrict__ ctr,        // [B,N]
    const float* __restrict__ gts,         // [B,G,4]
    unsigned long long* __restrict__ best) // [B*N]
{
#pragma clang fp contract(off)
  __shared__ float s_d[CAP];
  __shared__ int   s_i[CAP];
  __shared__ int   s_cnt;
  __shared__ int   s_sel[TOPK];
  __shared__ float s_iou[TOPK];
  __shared__ int   s_in[TOPK];
  __shared__ float s_thresh;

  const int bg  = blockIdx.x;
  const int b   = bg / G;
  const int g   = bg % G;
  const int tid = threadIdx.x;

  const float4 gbox = ((const float4*)gts)[bg];
  const float g_cx = (gbox.z + gbox.x) * 0.5f;
  const float g_cy = (gbox.w + gbox.y) * 0.5f;

  const float4*  abase = (const float4*)(anchors + (size_t)b * N * 4);
  const float2*  cbase = ctr + (size_t)b * N;

  // --- Candidate collection: all anchors with dist < thr (exact count). ---
  float thr = 24.0f;
  int M = 0;
  for (int attempt = 0; attempt < 8; ++attempt) {
    if (tid == 0) s_cnt = 0;
    __syncthreads();
    for (int n = tid; n < N; n += 256) {
      float2 c = cbase[n];
      float dx = c.x - g_cx, dy = c.y - g_cy;
      float d = __fsqrt_rn(__fmul_rn(dx, dx) + __fmul_rn(dy, dy));
      if (d < thr) {
        int p = atomicAdd(&s_cnt, 1);
        if (p < CAP) { s_d[p] = d; s_i[p] = n; }
      }
    }
    __syncthreads();
    int cnt = s_cnt;
    __syncthreads();
    if (cnt >= TOPK && cnt <= CAP) { M = cnt; break; }
    thr = (cnt < TOPK) ? thr * 4.0f : thr * 0.5f;
  }

  // --- Exact top-27 by rank counting over (d, idx) lexicographic keys. ---
  for (int s = tid; s < M; s += 256) {
    unsigned long long pk_s =
        ((unsigned long long)__float_as_uint(s_d[s]) << 20) |
        (unsigned long long)(unsigned)s_i[s];
    int rank = 0;
    for (int j = 0; j < M; ++j) {
      unsigned long long pk_j =
          ((unsigned long long)__float_as_uint(s_d[j]) << 20) |
          (unsigned long long)(unsigned)s_i[j];
      rank += (pk_j < pk_s) ? 1 : 0;
    }
    if (rank < TOPK) s_sel[rank] = s_i[s];
  }
  __syncthreads();

  // --- Candidate IoU + center-inside test. ---
  if (tid < TOPK) {
    int a = s_sel[tid];
    float4 ab = abase[a];
    float area_a = __fmul_rn(ab.z - ab.x, ab.w - ab.y);
    float area_b = __fmul_rn(gbox.z - gbox.x, gbox.w - gbox.y);
    float ltx = fmaxf(ab.x, gbox.x), lty = fmaxf(ab.y, gbox.y);
    float rbx = fminf(ab.z, gbox.z), rby = fminf(ab.w, gbox.w);
    float w = fmaxf(rbx - ltx, 0.0f), h = fmaxf(rby - lty, 0.0f);
    float inter = __fmul_rn(w, h);
    float uni = (area_a + area_b) - inter;
    s_iou[tid] = inter / uni;
    float acx = (ab.z + ab.x) * 0.5f, acy = (ab.w + ab.y) * 0.5f;
    float l = acx - gbox.x, t = acy - gbox.y;
    float r = gbox.z - acx, bt = gbox.w - acy;
    float mn = fminf(fminf(l, t), fminf(r, bt));
    s_in[tid] = (mn > 0.01f) ? 1 : 0;
  }
  __syncthreads();

  // --- mean + unbiased std threshold (ddof=1). ---
  if (tid == 0) {
    float sum = 0.0f;
    for (int k = 0; k < TOPK; ++k) sum += s_iou[k];
    float mean = sum / (float)TOPK;
    float vs = 0.0f;
    for (int k = 0; k < TOPK; ++k) {
      float d = s_iou[k] - mean;
      vs += __fmul_rn(d, d);
    }
    float sd = __fsqrt_rn(vs / (float)(TOPK - 1));
    s_thresh = mean + sd;
  }
  __syncthreads();

  // --- Scatter positives. ---
  if (tid < TOPK) {
    float iou = s_iou[tid];
    if (s_in[tid] && iou >= s_thresh) {
      unsigned long long pk =
          ((unsigned long long)__float_as_uint(iou) << 32) |
          (unsigned long long)(0xFFFFFFFFu - (unsigned)g);
      atomicMax(&best[(size_t)b * N + s_sel[tid]], pk);
    }
  }
}

// ---------------------------------------------------------------------------
// Kernel C: per-anchor decode, done ONCE here so the bulk token kernel is a
// pure stream. Emits val/idx (dword coalesced), matched_gts (float4
// coalesced), and rowbuf[i] = gt row (b*G+g) if matched else -1.
// ---------------------------------------------------------------------------
__global__ __launch_bounds__(256) void atss_post_kernel(
    const unsigned long long* __restrict__ best, // [B*N]
    const float* __restrict__ gts,               // [B,G,4]
    float* __restrict__ out,
    int* __restrict__ rowbuf)
{
  const int i = blockIdx.x * 256 + threadIdx.x;
  unsigned long long p = best[i];
  const int b_ = i / N;
  int g = 0;
  float val = NEG_INF_VAL;
  if (p != 0ULL) {
    g   = (int)(0xFFFFFFFFu - (unsigned)(p & 0xFFFFFFFFULL));
    val = __uint_as_float((unsigned)(p >> 32));
  }
  const int row = b_ * G + g; // unmatched -> g=0 (matches argmax of all -INF)

  out[i] = val;
  out[(size_t)BN + i] = (float)g;
  ((float4*)(out + (size_t)2 * BN))[i] = ((const float4*)gts)[row];
  rowbuf[i] = (p != 0ULL) ? row : -1;
}

// ---------------------------------------------------------------------------
// Kernel T: bulk token-row stream, structured like the rocclr fill kernel.
// One wave per row; each wave owns ROWS_PER_WAVE contiguous rows -> its
// store stream is sequential (98 KB). Body: broadcast 4B rowbuf read ->
// wave-uniform branch -> 1 KB float4 store. Matched rows (~1.7%) read the
// 512 KB L2-resident token table.
// ---------------------------------------------------------------------------
constexpr int TW_BLOCKS = 2048;                       // 8192 waves
constexpr int ROWS_PER_WAVE = (BN + 8191) / 8192;     // 98

__global__ __launch_bounds__(256) void atss_tok_kernel(
    const int* __restrict__ rowbuf,   // [BN]
    const float* __restrict__ tokens, // [B,G,T]
    float* __restrict__ out_tok)      // [BN,T]
{
  const int wv   = (blockIdx.x * 256 + threadIdx.x) >> 6;
  const int lane = threadIdx.x & 63;
  const float4* tok4 = (const float4*)tokens;
  float4* o4 = (float4*)out_tok;

  const int r0 = wv * ROWS_PER_WAVE;
  const int r1 = (r0 + ROWS_PER_WAVE < BN) ? r0 + ROWS_PER_WAVE : BN;
#pragma unroll 2
  for (int row = r0; row < r1; ++row) {
    int r = rowbuf[row];
    float4 t;
    if (r >= 0) {
      t = tok4[(size_t)r * 64 + lane];
    } else {
      t = make_float4(0.0f, 0.0f, 0.0f, (lane == 63) ? 1.0f : 0.0f);
    }
    o4[(size_t)row * 64 + lane] = t;
  }
}

extern "C" void kernel_launch(void* const* d_in, const int* in_sizes, int n_in,
                              void* d_out, int out_size, void* d_ws, size_t ws_size,
                              hipStream_t stream) {
  const float* anchors = (const float*)d_in[0]; // [B,N,4]
  const float* gts     = (const float*)d_in[1]; // [B,G,4]
  const float* tokens  = (const float*)d_in[2]; // [B,G,T]
  float* out = (float*)d_out;

  unsigned long long* best = (unsigned long long*)d_ws;               // 6.4 MB
  float2* ctr = (float2*)((char*)d_ws + sizeof(unsigned long long) * (size_t)BN);
  int* rowbuf = (int*)((char*)d_ws + (sizeof(unsigned long long) + sizeof(float2)) * (size_t)BN);

  atss_prep_kernel<<<(BN + 255) / 256, 256, 0, stream>>>(anchors, ctr, best);
  atss_assign_kernel<<<B * G, 256, 0, stream>>>(anchors, ctr, gts, best);
  atss_post_kernel<<<BN / 256, 256, 0, stream>>>(best, gts, out, rowbuf);
  atss_tok_kernel<<<TW_BLOCKS, 256, 0, stream>>>(rowbuf, tokens, out + (size_t)6 * BN);
}

// Round 5
// 978.061 us; speedup vs baseline: 1.0206x; 1.0016x over previous
//
#include <hip/hip_runtime.h>
#include <cstdint>

// Problem constants (fixed dataset: setup_inputs in reference)
constexpr int B = 8, N = 100000, G = 64, T = 256, TOPK = 27;
constexpr int BN = B * N;
constexpr int CAP = 2048;           // candidate LDS capacity per gt
constexpr int MAXM = B * G * TOPK;  // max matched anchors = 13824
#define NEG_INF_VAL (-100000000.0f) // -INF in reference, exactly representable

// ---------------------------------------------------------------------------
// Kernel P: fused prep — zero best[] + match counter, precompute centers
// (same formula as assign/iou so distances are bit-identical).
// ---------------------------------------------------------------------------
__global__ __launch_bounds__(256) void atss_prep_kernel(
    const float* __restrict__ anchors, float2* __restrict__ ctr,
    unsigned long long* __restrict__ best, int* __restrict__ mcnt)
{
#pragma clang fp contract(off)
  int i = blockIdx.x * 256 + threadIdx.x;
  if (i == 0) *mcnt = 0;
  if (i < BN) {
    best[i] = 0ULL;
    float4 ab = ((const float4*)anchors)[i];
    ctr[i] = make_float2((ab.z + ab.x) * 0.5f, (ab.w + ab.y) * 0.5f);
  }
}

// ---------------------------------------------------------------------------
// Kernel A: one block per (b,g). Exact top-27 nearest anchors by center
// distance (tie-break: lower index, matching lax.top_k), candidate IoUs,
// mean + unbiased std threshold (ddof=1), center-inside test, packed
// atomicMax scatter into per-anchor best buffer.
// packed = (f32bits(iou) << 32) | (0xFFFFFFFF - g)
//   -> max = largest iou; tie -> smallest g (matches jnp.argmax first-max).
// packed == 0 means "unmatched" (positives always have iou > 0).
// NUMERICS UNCHANGED since round 2 (absmax 0.0) — do not touch.
// ---------------------------------------------------------------------------
__global__ __launch_bounds__(256) void atss_assign_kernel(
    const float* __restrict__ anchors,     // [B,N,4]
    const float2* __restrict__ ctr,        // [B,N]
    const float* __restrict__ gts,         // [B,G,4]
    unsigned long long* __restrict__ best) // [B*N]
{
#pragma clang fp contract(off)
  __shared__ float s_d[CAP];
  __shared__ int   s_i[CAP];
  __shared__ int   s_cnt;
  __shared__ int   s_sel[TOPK];
  __shared__ float s_iou[TOPK];
  __shared__ int   s_in[TOPK];
  __shared__ float s_thresh;

  const int bg  = blockIdx.x;
  const int b   = bg / G;
  const int g   = bg % G;
  const int tid = threadIdx.x;

  const float4 gbox = ((const float4*)gts)[bg];
  const float g_cx = (gbox.z + gbox.x) * 0.5f;
  const float g_cy = (gbox.w + gbox.y) * 0.5f;

  const float4*  abase = (const float4*)(anchors + (size_t)b * N * 4);
  const float2*  cbase = ctr + (size_t)b * N;

  // --- Candidate collection: all anchors with dist < thr (exact count). ---
  float thr = 24.0f;
  int M = 0;
  for (int attempt = 0; attempt < 8; ++attempt) {
    if (tid == 0) s_cnt = 0;
    __syncthreads();
    for (int n = tid; n < N; n += 256) {
      float2 c = cbase[n];
      float dx = c.x - g_cx, dy = c.y - g_cy;
      float d = __fsqrt_rn(__fmul_rn(dx, dx) + __fmul_rn(dy, dy));
      if (d < thr) {
        int p = atomicAdd(&s_cnt, 1);
        if (p < CAP) { s_d[p] = d; s_i[p] = n; }
      }
    }
    __syncthreads();
    int cnt = s_cnt;
    __syncthreads();
    if (cnt >= TOPK && cnt <= CAP) { M = cnt; break; }
    thr = (cnt < TOPK) ? thr * 4.0f : thr * 0.5f;
  }

  // --- Exact top-27 by rank counting over (d, idx) lexicographic keys. ---
  for (int s = tid; s < M; s += 256) {
    unsigned long long pk_s =
        ((unsigned long long)__float_as_uint(s_d[s]) << 20) |
        (unsigned long long)(unsigned)s_i[s];
    int rank = 0;
    for (int j = 0; j < M; ++j) {
      unsigned long long pk_j =
          ((unsigned long long)__float_as_uint(s_d[j]) << 20) |
          (unsigned long long)(unsigned)s_i[j];
      rank += (pk_j < pk_s) ? 1 : 0;
    }
    if (rank < TOPK) s_sel[rank] = s_i[s];
  }
  __syncthreads();

  // --- Candidate IoU + center-inside test. ---
  if (tid < TOPK) {
    int a = s_sel[tid];
    float4 ab = abase[a];
    float area_a = __fmul_rn(ab.z - ab.x, ab.w - ab.y);
    float area_b = __fmul_rn(gbox.z - gbox.x, gbox.w - gbox.y);
    float ltx = fmaxf(ab.x, gbox.x), lty = fmaxf(ab.y, gbox.y);
    float rbx = fminf(ab.z, gbox.z), rby = fminf(ab.w, gbox.w);
    float w = fmaxf(rbx - ltx, 0.0f), h = fmaxf(rby - lty, 0.0f);
    float inter = __fmul_rn(w, h);
    float uni = (area_a + area_b) - inter;
    s_iou[tid] = inter / uni;
    float acx = (ab.z + ab.x) * 0.5f, acy = (ab.w + ab.y) * 0.5f;
    float l = acx - gbox.x, t = acy - gbox.y;
    float r = gbox.z - acx, bt = gbox.w - acy;
    float mn = fminf(fminf(l, t), fminf(r, bt));
    s_in[tid] = (mn > 0.01f) ? 1 : 0;
  }
  __syncthreads();

  // --- mean + unbiased std threshold (ddof=1). ---
  if (tid == 0) {
    float sum = 0.0f;
    for (int k = 0; k < TOPK; ++k) sum += s_iou[k];
    float mean = sum / (float)TOPK;
    float vs = 0.0f;
    for (int k = 0; k < TOPK; ++k) {
      float d = s_iou[k] - mean;
      vs += __fmul_rn(d, d);
    }
    float sd = __fsqrt_rn(vs / (float)(TOPK - 1));
    s_thresh = mean + sd;
  }
  __syncthreads();

  // --- Scatter positives. ---
  if (tid < TOPK) {
    float iou = s_iou[tid];
    if (s_in[tid] && iou >= s_thresh) {
      unsigned long long pk =
          ((unsigned long long)__float_as_uint(iou) << 32) |
          (unsigned long long)(0xFFFFFFFFu - (unsigned)g);
      atomicMax(&best[(size_t)b * N + s_sel[tid]], pk);
    }
  }
}

// ---------------------------------------------------------------------------
// Kernel C: per-anchor decode + compaction. Emits val/idx (dword coalesced),
// matched_gts (float4 coalesced), and appends matched anchors to a compact
// (anchor, row) list via one global atomic counter (<= 13824 entries).
// ---------------------------------------------------------------------------
__global__ __launch_bounds__(256) void atss_post_kernel(
    const unsigned long long* __restrict__ best, // [B*N]
    const float* __restrict__ gts,               // [B,G,4]
    float* __restrict__ out,
    int* __restrict__ mcnt,
    int2* __restrict__ mlist)
{
  const int i = blockIdx.x * 256 + threadIdx.x;
  unsigned long long p = best[i];
  const int b_ = i / N;
  int g = 0;
  float val = NEG_INF_VAL;
  if (p != 0ULL) {
    g   = (int)(0xFFFFFFFFu - (unsigned)(p & 0xFFFFFFFFULL));
    val = __uint_as_float((unsigned)(p >> 32));
  }
  const int row = b_ * G + g; // unmatched -> g=0 (matches argmax of all -INF)

  out[i] = val;
  out[(size_t)BN + i] = (float)g;
  ((float4*)(out + (size_t)2 * BN))[i] = ((const float4*)gts)[row];
  if (p != 0ULL) {
    int s = atomicAdd(mcnt, 1);
    mlist[s] = make_int2(i, row);
  }
}

// ---------------------------------------------------------------------------
// Kernel T: STORE-ONLY bulk token writer. Writes every row as the unmatched
// pattern. Grid-stride is a multiple of 64 float4s, so (idx & 63) — hence the
// store value — is loop-invariant: the body is one address add + one
// global_store_dwordx4, structurally identical to the rocclr fill kernel.
// ---------------------------------------------------------------------------
constexpr long long TOK4 = (long long)BN * 64;   // 51,200,000 float4s
constexpr int TB_BLOCKS = 8192;                  // stride = 2,097,152 (mult of 64)

__global__ __launch_bounds__(256) void atss_tok_bulk_kernel(
    float* __restrict__ out_tok)
{
  const long long flat = (long long)blockIdx.x * 256 + threadIdx.x;
  const long long stride = (long long)TB_BLOCKS * 256;
  const float4 t = make_float4(0.0f, 0.0f, 0.0f,
                               ((flat & 63) == 63) ? 1.0f : 0.0f);
  float4* o4 = (float4*)out_tok;
  for (long long i = flat; i < TOK4; i += stride) o4[i] = t;
}

// ---------------------------------------------------------------------------
// Kernel F: fix-up — one wave per matched anchor overwrites its token row
// with the real gt token row (1 KB copy; token table is L2-resident).
// ---------------------------------------------------------------------------
__global__ __launch_bounds__(256) void atss_fix_kernel(
    const int* __restrict__ mcnt,
    const int2* __restrict__ mlist,
    const float* __restrict__ tokens, // [B,G,T]
    float* __restrict__ out_tok)      // [BN,T]
{
  const int s    = (blockIdx.x * 256 + threadIdx.x) >> 6;
  const int lane = threadIdx.x & 63;
  if (s >= *mcnt) return;
  int2 e = mlist[s];
  ((float4*)(out_tok + (size_t)e.x * T))[lane] =
      ((const float4*)tokens)[(size_t)e.y * 64 + lane];
}

extern "C" void kernel_launch(void* const* d_in, const int* in_sizes, int n_in,
                              void* d_out, int out_size, void* d_ws, size_t ws_size,
                              hipStream_t stream) {
  const float* anchors = (const float*)d_in[0]; // [B,N,4]
  const float* gts     = (const float*)d_in[1]; // [B,G,4]
  const float* tokens  = (const float*)d_in[2]; // [B,G,T]
  float* out = (float*)d_out;
  float* out_tok = out + (size_t)6 * BN;

  char* ws = (char*)d_ws;
  unsigned long long* best = (unsigned long long*)ws;          // 6.4 MB
  float2* ctr  = (float2*)(ws + 8 * (size_t)BN);               // 6.4 MB
  int*    mcnt = (int*)(ws + 16 * (size_t)BN);                 // 4 B (+pad)
  int2*   mlist = (int2*)(ws + 16 * (size_t)BN + 256);         // 108 KB

  atss_prep_kernel<<<(BN + 255) / 256, 256, 0, stream>>>(anchors, ctr, best, mcnt);
  atss_assign_kernel<<<B * G, 256, 0, stream>>>(anchors, ctr, gts, best);
  atss_post_kernel<<<BN / 256, 256, 0, stream>>>(best, gts, out, mcnt, mlist);
  atss_tok_bulk_kernel<<<TB_BLOCKS, 256, 0, stream>>>(out_tok);
  atss_fix_kernel<<<(MAXM + 3) / 4, 256, 0, stream>>>(mcnt, mlist, tokens, out_tok);
}